// Round 5
// baseline (7244.158 us; speedup 1.0000x reference)
//
#include <hip/hip_runtime.h>
#include <hip/hip_bf16.h>
#include <math.h>

#define B_ 2048
#define L_ 32
#define V_ 1024
#define E_ 256
#define H_ 512
#define DEC_T_ 7

typedef unsigned short u16;

__device__ __forceinline__ u16 f2b(float f) {
  union { float f; unsigned int i; } x; x.f = f;
  unsigned int r = x.i + 0x7FFFu + ((x.i >> 16) & 1u);
  return (u16)(r >> 16);
}
__device__ __forceinline__ float b2f(u16 u) {
  union { unsigned int i; float f; } x; x.i = ((unsigned int)u) << 16; return x.f;
}
__device__ __forceinline__ float sigm(float x) { return 1.f / (1.f + __expf(-x)); }

// ---------------------------------------------------------------------------
// Fused LSTM step GEMM, all fp32. Gate-interleaved columns: GEMM col j ->
// n = j>>2, gate = j&3, weight row worig = (j&3)*H + (j>>2); each thread's 4
// consecutive columns are the 4 gates of one hidden unit, so the LSTM cell
// applies in the epilogue. Encoder (feat != null): A = [emb[tok] | h_in],
// K = E+H. Decoder: A = h_in, K = H.
// ---------------------------------------------------------------------------
struct LP {
  const int* feat;        // token for row m at feat[m*L_]; null => decoder
  const float* emb;       // V x E
  const float* h_in;      // B x H
  const float* Wih;       // 4H x E (encoder only)
  const float* Whh;       // 4H x H
  const float* b1; const float* b2;   // 4H
  float* h_out;           // B x H
  float* c;               // B x H (in-place)
  int K;
};

__launch_bounds__(256)
__global__ void lstm_gemm_k(LP p0, LP p1) {
  LP p = (blockIdx.z == 0) ? p0 : p1;
  __shared__ float As[8][128];
  __shared__ float Bs[8][128];
  const int tid = threadIdx.x;
  const int tx = tid & 15, ty = tid >> 4;
  const int m0 = blockIdx.y * 128, n0 = blockIdx.x * 128;
  const int lrow = tid >> 1, lcg = (tid & 1) * 4;
  const int gm = m0 + lrow, gn = n0 + lrow;
  const int worig = (gn & 3) * H_ + (gn >> 2);

  float acc[8][8];
#pragma unroll
  for (int i = 0; i < 8; ++i)
#pragma unroll
    for (int j = 0; j < 8; ++j) acc[i][j] = 0.f;

  for (int k0 = 0; k0 < p.K; k0 += 8) {
    const int k = k0 + lcg;
    float4 av, bv;
    if (p.feat) {
      if (k < E_) {
        const int tok = p.feat[gm * L_];
        av = *(const float4*)(p.emb + tok * E_ + k);
        bv = *(const float4*)(p.Wih + worig * E_ + k);
      } else {
        av = *(const float4*)(p.h_in + gm * H_ + (k - E_));
        bv = *(const float4*)(p.Whh + worig * H_ + (k - E_));
      }
    } else {
      av = *(const float4*)(p.h_in + gm * H_ + k);
      bv = *(const float4*)(p.Whh + worig * H_ + k);
    }
    __syncthreads();
    As[lcg + 0][lrow] = av.x; As[lcg + 1][lrow] = av.y;
    As[lcg + 2][lrow] = av.z; As[lcg + 3][lrow] = av.w;
    Bs[lcg + 0][lrow] = bv.x; Bs[lcg + 1][lrow] = bv.y;
    Bs[lcg + 2][lrow] = bv.z; Bs[lcg + 3][lrow] = bv.w;
    __syncthreads();
#pragma unroll
    for (int kk = 0; kk < 8; ++kk) {
      const float4 a0 = *(const float4*)&As[kk][ty * 4];
      const float4 a1 = *(const float4*)&As[kk][ty * 4 + 64];
      const float4 b0 = *(const float4*)&Bs[kk][tx * 4];
      const float4 b1 = *(const float4*)&Bs[kk][tx * 4 + 64];
      const float ar[8] = {a0.x, a0.y, a0.z, a0.w, a1.x, a1.y, a1.z, a1.w};
      const float br[8] = {b0.x, b0.y, b0.z, b0.w, b1.x, b1.y, b1.z, b1.w};
#pragma unroll
      for (int i = 0; i < 8; ++i)
#pragma unroll
        for (int j = 0; j < 8; ++j)
          acc[i][j] = fmaf(ar[i], br[j], acc[i][j]);
    }
  }

  int nn[2]; float bg[2][4];
#pragma unroll
  for (int jh = 0; jh < 2; ++jh) {
    nn[jh] = (n0 >> 2) + jh * 16 + tx;
#pragma unroll
    for (int g = 0; g < 4; ++g)
      bg[jh][g] = p.b1[g * H_ + nn[jh]] + p.b2[g * H_ + nn[jh]];
  }
#pragma unroll
  for (int ih = 0; ih < 2; ++ih)
#pragma unroll
    for (int ii = 0; ii < 4; ++ii) {
      const int i = ih * 4 + ii;
      const int m = m0 + ih * 64 + ty * 4 + ii;
#pragma unroll
      for (int jh = 0; jh < 2; ++jh) {
        const float gi = acc[i][jh * 4 + 0] + bg[jh][0];
        const float gf = acc[i][jh * 4 + 1] + bg[jh][1];
        const float gg = acc[i][jh * 4 + 2] + bg[jh][2];
        const float go = acc[i][jh * 4 + 3] + bg[jh][3];
        const int idx = m * H_ + nn[jh];
        const float cn = sigm(gf) * p.c[idx] + sigm(gi) * tanhf(gg);
        const float hn = sigm(go) * tanhf(cn);
        p.c[idx] = cn;
        p.h_out[idx] = hn;
      }
    }
}

// ---------------------------------------------------------------------------
// Output GEMM, all fp32: C = A @ W^T + bias. If mean != null, A is LayerNorm
// of concat(A0,A1) with per-row mean/rstd (precomputed) and affine lng/lnb.
// ---------------------------------------------------------------------------
struct OP {
  const float* A0; const float* A1; int lda;
  const float* mean; const float* rstd; const float* lng; const float* lnb;
  const float* W; int ldw;
  const float* bias;
  float* Cf; long ldcf;
  int K;
};

__launch_bounds__(256)
__global__ void out_gemm_k(OP p0, OP p1) {
  OP p = (blockIdx.z == 0) ? p0 : p1;
  __shared__ float As[8][128];
  __shared__ float Bs[8][128];
  const int tid = threadIdx.x;
  const int tx = tid & 15, ty = tid >> 4;
  const int m0 = blockIdx.y * 128, n0 = blockIdx.x * 128;
  const int lrow = tid >> 1, lcg = (tid & 1) * 4;
  const int gm = m0 + lrow, gn = n0 + lrow;
  float rm = 0.f, rs = 0.f;
  if (p.mean) { rm = p.mean[gm]; rs = p.rstd[gm]; }

  float acc[8][8];
#pragma unroll
  for (int i = 0; i < 8; ++i)
#pragma unroll
    for (int j = 0; j < 8; ++j) acc[i][j] = 0.f;

  for (int k0 = 0; k0 < p.K; k0 += 8) {
    const int k = k0 + lcg;
    float4 av;
    const float4 w4 = *(const float4*)(p.W + (long)gn * p.ldw + k);
    if (p.mean) {
      const float4 x4 = (k < H_) ? *(const float4*)(p.A0 + gm * H_ + k)
                                 : *(const float4*)(p.A1 + gm * H_ + (k - H_));
      const float4 g4 = *(const float4*)(p.lng + k);
      const float4 b4 = *(const float4*)(p.lnb + k);
      av.x = (x4.x - rm) * rs * g4.x + b4.x;
      av.y = (x4.y - rm) * rs * g4.y + b4.y;
      av.z = (x4.z - rm) * rs * g4.z + b4.z;
      av.w = (x4.w - rm) * rs * g4.w + b4.w;
    } else {
      av = *(const float4*)(p.A0 + gm * p.lda + k);
    }
    __syncthreads();
    As[lcg + 0][lrow] = av.x; As[lcg + 1][lrow] = av.y;
    As[lcg + 2][lrow] = av.z; As[lcg + 3][lrow] = av.w;
    Bs[lcg + 0][lrow] = w4.x; Bs[lcg + 1][lrow] = w4.y;
    Bs[lcg + 2][lrow] = w4.z; Bs[lcg + 3][lrow] = w4.w;
    __syncthreads();
#pragma unroll
    for (int kk = 0; kk < 8; ++kk) {
      const float4 a0 = *(const float4*)&As[kk][ty * 4];
      const float4 a1 = *(const float4*)&As[kk][ty * 4 + 64];
      const float4 b0 = *(const float4*)&Bs[kk][tx * 4];
      const float4 b1 = *(const float4*)&Bs[kk][tx * 4 + 64];
      const float ar[8] = {a0.x, a0.y, a0.z, a0.w, a1.x, a1.y, a1.z, a1.w};
      const float br[8] = {b0.x, b0.y, b0.z, b0.w, b1.x, b1.y, b1.z, b1.w};
#pragma unroll
      for (int i = 0; i < 8; ++i)
#pragma unroll
        for (int j = 0; j < 8; ++j)
          acc[i][j] = fmaf(ar[i], br[j], acc[i][j]);
    }
  }

  float bias[8];
#pragma unroll
  for (int jh = 0; jh < 2; ++jh)
#pragma unroll
    for (int jj = 0; jj < 4; ++jj)
      bias[jh * 4 + jj] = p.bias[n0 + jh * 64 + tx * 4 + jj];

#pragma unroll
  for (int ih = 0; ih < 2; ++ih)
#pragma unroll
    for (int ii = 0; ii < 4; ++ii) {
      const int i = ih * 4 + ii;
      const int m = m0 + ih * 64 + ty * 4 + ii;
#pragma unroll
      for (int jh = 0; jh < 2; ++jh) {
        float4 v;
        v.x = acc[i][jh * 4 + 0] + bias[jh * 4 + 0];
        v.y = acc[i][jh * 4 + 1] + bias[jh * 4 + 1];
        v.z = acc[i][jh * 4 + 2] + bias[jh * 4 + 2];
        v.w = acc[i][jh * 4 + 3] + bias[jh * 4 + 3];
        *(float4*)(p.Cf + (long)m * p.ldcf + n0 + jh * 64 + tx * 4) = v;
      }
    }
}

__global__ void init_k(float* a, float* b, float* c, float* d) {
  const int i = blockIdx.x * 256 + threadIdx.x;
  a[i] = 0.f; b[i] = 0.f; c[i] = 0.f; d[i] = 0.f;
}

// echo features as fp32 on the bf16 grid (matches the np ref exactly)
__global__ void cast_feat_k(const int* f, float* o) {
  const int i = blockIdx.x * 256 + threadIdx.x;
  o[i] = b2f(f2b((float)f[i]));
}

__global__ void ln_stats_k(const float* hf, const float* hb, float* mean, float* rstd) {
  const int b = blockIdx.x, t = threadIdx.x;
  float s = 0.f, sq = 0.f;
#pragma unroll
  for (int j = 0; j < 4; ++j) {
    const int k = t + 256 * j;
    const float v = (k < H_) ? hf[b * H_ + k] : hb[b * H_ + (k - H_)];
    s += v; sq += v * v;
  }
#pragma unroll
  for (int off = 32; off; off >>= 1) {
    s += __shfl_down(s, off);
    sq += __shfl_down(sq, off);
  }
  __shared__ float ss[4], ssq[4];
  if ((t & 63) == 0) { ss[t >> 6] = s; ssq[t >> 6] = sq; }
  __syncthreads();
  if (t == 0) {
    const float S = ss[0] + ss[1] + ss[2] + ss[3];
    const float SQ = ssq[0] + ssq[1] + ssq[2] + ssq[3];
    const float m = S * (1.f / 1024.f);
    const float var = SQ * (1.f / 1024.f) - m * m;
    mean[b] = m;
    rstd[b] = rsqrtf(var + 1e-5f);
  }
}

__global__ void z_k(const float* mu, const float* lv, const float* eps,
                    float* dh, float* dc) {
  const int i = blockIdx.x * 256 + threadIdx.x;
  const float z = mu[i] + __expf(0.5f * lv[i]) * eps[i];
  dh[i] = z; dc[i] = z;
}

extern "C" void kernel_launch(void* const* d_in, const int* in_sizes, int n_in,
                              void* d_out, int out_size, void* d_ws, size_t ws_size,
                              hipStream_t stream) {
  const int*   features = (const int*)d_in[0];
  const float* eps      = (const float*)d_in[1];
  const float* emb      = (const float*)d_in[2];
  const float* eWih_f   = (const float*)d_in[3];
  const float* eWhh_f   = (const float*)d_in[4];
  const float* ebih_f   = (const float*)d_in[5];
  const float* ebhh_f   = (const float*)d_in[6];
  const float* eWih_b   = (const float*)d_in[7];
  const float* eWhh_b   = (const float*)d_in[8];
  const float* ebih_b   = (const float*)d_in[9];
  const float* ebhh_b   = (const float*)d_in[10];
  const float* dWhh     = (const float*)d_in[12];
  const float* dbih     = (const float*)d_in[13];
  const float* dbhh     = (const float*)d_in[14];
  const float* mu_ln_g  = (const float*)d_in[15];
  const float* mu_ln_b  = (const float*)d_in[16];
  const float* mu_W     = (const float*)d_in[17];
  const float* mu_b     = (const float*)d_in[18];
  const float* lv_ln_g  = (const float*)d_in[19];
  const float* lv_ln_b  = (const float*)d_in[20];
  const float* lv_W     = (const float*)d_in[21];
  const float* lv_b     = (const float*)d_in[22];
  const float* ff_W     = (const float*)d_in[23];
  const float* ff_b     = (const float*)d_in[24];

  // d_out is FP32: [features 65536 | features_hat 14680064 | mu 1048576 | lv 1048576]
  float* of = (float*)d_out;
  float* o_feat = of;
  float* o_fh   = of + (B_ * L_);
  float* o_mu   = o_fh + (long)B_ * DEC_T_ * V_;
  float* o_lv   = o_mu + (long)B_ * H_;

  // d_ws: 6 x (B*H fp32 = 4MB) + stats = 24.02 MB
  const int NA = B_ * H_;
  float* hf0 = (float*)d_ws;     // enc fwd h ping  -> dec h pong
  float* hf1 = hf0 + NA;         // enc fwd h pong  -> dec h ping (z)
  float* hb0 = hf1 + NA;         // enc bwd h ping
  float* hb1 = hb0 + NA;         // enc bwd h pong  -> dec c (z)
  float* cf  = hb1 + NA;         // enc fwd c
  float* cb  = cf  + NA;         // enc bwd c
  float* mean = cb + NA;         // 2048
  float* rstd = mean + B_;       // 2048

  cast_feat_k<<<dim3(B_ * L_ / 256), dim3(256), 0, stream>>>(features, o_feat);
  init_k<<<dim3(NA / 256), dim3(256), 0, stream>>>(hf0, hb0, cf, cb);

  // ---- encoder: 32 dual-direction fused steps ------------------------------
  for (int s = 0; s < L_; ++s) {
    LP pf{}, pb{};
    pf.feat = features + s;              pb.feat = features + (L_ - 1 - s);
    pf.emb = emb;                        pb.emb = emb;
    pf.h_in  = (s & 1) ? hf1 : hf0;      pb.h_in  = (s & 1) ? hb1 : hb0;
    pf.h_out = (s & 1) ? hf0 : hf1;      pb.h_out = (s & 1) ? hb0 : hb1;
    pf.Wih = eWih_f;  pf.Whh = eWhh_f;   pb.Wih = eWih_b;  pb.Whh = eWhh_b;
    pf.b1 = ebih_f;   pf.b2 = ebhh_f;    pb.b1 = ebih_b;   pb.b2 = ebhh_b;
    pf.c = cf;                           pb.c = cb;
    pf.K = E_ + H_;                      pb.K = E_ + H_;
    lstm_gemm_k<<<dim3(16, 16, 2), dim3(256), 0, stream>>>(pf, pb);
  }
  // 32 (even) steps done: final fwd h in hf0, bwd h in hb0.

  // ---- LN stats + mu/lv heads (direct fp32 output) -------------------------
  ln_stats_k<<<dim3(B_), dim3(256), 0, stream>>>(hf0, hb0, mean, rstd);
  {
    OP pm{}, pl{};
    pm.A0 = hf0; pm.A1 = hb0; pm.lda = 0;
    pm.mean = mean; pm.rstd = rstd; pm.lng = mu_ln_g; pm.lnb = mu_ln_b;
    pm.W = mu_W; pm.ldw = 2 * H_;
    pm.bias = mu_b;
    pm.Cf = o_mu; pm.ldcf = H_;
    pm.K = 2 * H_;
    pl = pm;
    pl.lng = lv_ln_g; pl.lnb = lv_ln_b;
    pl.W = lv_W; pl.bias = lv_b;
    pl.Cf = o_lv;
    out_gemm_k<<<dim3(H_ / 128, 16, 2), dim3(256), 0, stream>>>(pm, pl);
  }
  // z seeds decoder: h ping = hf1 slot, c = hb1 slot, pong = hf0 slot
  z_k<<<dim3(NA / 256), dim3(256), 0, stream>>>(o_mu, o_lv, eps, hf1, hb1);

  // ---- decoder: 7 fused steps + ff projection ------------------------------
  for (int t = 0; t < DEC_T_; ++t) {
    LP pg{};
    pg.feat = nullptr; pg.emb = nullptr;
    pg.h_in  = (t & 1) ? hf0 : hf1;
    pg.h_out = (t & 1) ? hf1 : hf0;
    pg.Wih = nullptr; pg.Whh = dWhh;
    pg.b1 = dbih; pg.b2 = dbhh;
    pg.c = hb1;
    pg.K = H_;
    lstm_gemm_k<<<dim3(16, 16, 1), dim3(256), 0, stream>>>(pg, pg);

    OP po{};
    po.A0 = pg.h_out; po.A1 = nullptr; po.lda = H_;
    po.mean = nullptr; po.rstd = nullptr; po.lng = nullptr; po.lnb = nullptr;
    po.W = ff_W; po.ldw = H_;
    po.bias = ff_b;
    po.Cf = o_fh + (long)t * V_; po.ldcf = DEC_T_ * V_;
    po.K = H_;
    out_gemm_k<<<dim3(V_ / 128, 16, 1), dim3(256), 0, stream>>>(po, po);
  }
}

// Round 6
// 2521.639 us; speedup vs baseline: 2.8728x; 2.8728x over previous
//
#include <hip/hip_runtime.h>
#include <hip/hip_bf16.h>
#include <math.h>

#define B_ 2048
#define L_ 32
#define V_ 1024
#define E_ 256
#define H_ 512
#define DEC_T_ 7

typedef unsigned short u16;
using bf16x8 = __attribute__((ext_vector_type(8))) short;
using f32x4  = __attribute__((ext_vector_type(4))) float;

__device__ __forceinline__ u16 f2b(float f) {
  union { float f; unsigned int i; } x; x.f = f;
  unsigned int r = x.i + 0x7FFFu + ((x.i >> 16) & 1u);
  return (u16)(r >> 16);
}
__device__ __forceinline__ float b2f(u16 u) {
  union { unsigned int i; float f; } x; x.i = ((unsigned int)u) << 16; return x.f;
}
__device__ __forceinline__ float sigm(float x) { return 1.f / (1.f + __expf(-x)); }
__device__ __forceinline__ float tanhfast(float x) {
  const float xx = fminf(fmaxf(x, -15.f), 15.f);
  const float e = __expf(2.f * xx);
  return (e - 1.f) / (e + 1.f);
}
// pack 8 fp32 -> 8 bf16 (RNE) and store 16B to LDS
__device__ __forceinline__ void st8bf(u16* dst, const float4 a, const float4 b) {
  __hip_bfloat162 p0 = __float22bfloat162_rn(make_float2(a.x, a.y));
  __hip_bfloat162 p1 = __float22bfloat162_rn(make_float2(a.z, a.w));
  __hip_bfloat162 p2 = __float22bfloat162_rn(make_float2(b.x, b.y));
  __hip_bfloat162 p3 = __float22bfloat162_rn(make_float2(b.z, b.w));
  uint4 v;
  v.x = *(unsigned int*)&p0; v.y = *(unsigned int*)&p1;
  v.z = *(unsigned int*)&p2; v.w = *(unsigned int*)&p3;
  *(uint4*)dst = v;
}

// ---------------------------------------------------------------------------
// Transposed fused LSTM gate GEMM (bf16 MFMA, fp32 accum):
//   G^T[j][m] = sum_k Wr[j][k] * act[m][k],  j = gate-interleaved (n*4+gate).
// C-layout: row=(lane>>4)*4+reg (j, ≡0 mod 4 per lane) => one lane holds all
// 4 gates of hidden unit n = j>>2 for batch m = col. Cell fused in epilogue.
// act = [emb[tok] | h_in] (K=E+H, encoder) or h_in (K=H, decoder), fp32,
// converted to bf16 during LDS staging. Wr pre-converted bf16 in ws.
// ---------------------------------------------------------------------------
struct LP {
  const int* feat;      // token for batch row m at feat[m*L_]; null => decoder
  const float* emb;     // V x E fp32
  const float* h_in;    // B x H fp32
  const u16* W;         // 2048 x K bf16, gate-interleaved rows
  const float* bsum;    // 2048 fp32, gate-interleaved (bih+bhh)
  float* h_out;         // B x H fp32
  float* c;             // B x H fp32 (in-place)
  int K;
};

__launch_bounds__(256)
__global__ void lstm_mfma_k(LP p0, LP p1) {
  LP p = blockIdx.z ? p1 : p0;
  __shared__ u16 Wt[128 * 40];   // weight tile, rows j, stride 40 (80B, 16B-mult)
  __shared__ u16 At[128 * 40];   // act tile, rows m
  const int tid = threadIdx.x;
  const int lane = tid & 63, wave = tid >> 6;
  const int wr = wave & 1, wc = wave >> 1;
  const int j0 = blockIdx.x * 128, m0 = blockIdx.y * 128;
  const int lr = lane & 15, lk = (lane >> 4) * 8;

  f32x4 acc[4][4] = {};

  for (int k0 = 0; k0 < p.K; k0 += 32) {
    uint4 wv[2]; float4 alo[2], ahi[2];
#pragma unroll
    for (int cc = 0; cc < 2; ++cc) {
      const int ch = tid + cc * 256;           // 0..511
      const int row = ch >> 2, kc = (ch & 3) * 8;
      const int k = k0 + kc;
      wv[cc] = *(const uint4*)(p.W + (j0 + row) * p.K + k);
      const float* src;
      if (p.feat) {
        if (k < E_) {
          const int tok = p.feat[(m0 + row) * L_];
          src = p.emb + tok * E_ + k;
        } else {
          src = p.h_in + (m0 + row) * H_ + (k - E_);
        }
      } else {
        src = p.h_in + (m0 + row) * H_ + k;
      }
      alo[cc] = *(const float4*)src;
      ahi[cc] = *(const float4*)(src + 4);
    }
    __syncthreads();
#pragma unroll
    for (int cc = 0; cc < 2; ++cc) {
      const int ch = tid + cc * 256;
      const int row = ch >> 2, kc = (ch & 3) * 8;
      *(uint4*)(Wt + row * 40 + kc) = wv[cc];
      st8bf(At + row * 40 + kc, alo[cc], ahi[cc]);
    }
    __syncthreads();
    bf16x8 af[4], bf[4];
#pragma unroll
    for (int t = 0; t < 4; ++t) {
      af[t] = *(const bf16x8*)(Wt + (wr * 64 + t * 16 + lr) * 40 + lk);
      bf[t] = *(const bf16x8*)(At + (wc * 64 + t * 16 + lr) * 40 + lk);
    }
#pragma unroll
    for (int i = 0; i < 4; ++i)
#pragma unroll
      for (int j = 0; j < 4; ++j)
        acc[i][j] = __builtin_amdgcn_mfma_f32_16x16x32_bf16(af[i], bf[j], acc[i][j], 0, 0, 0);
  }

  // epilogue: lane's 4 regs = gates i,f,g,o of n; scattered fp32 h/c update
#pragma unroll
  for (int i = 0; i < 4; ++i) {
    const int jb = j0 + wr * 64 + i * 16 + (lane >> 4) * 4;   // ≡ 0 mod 4
    const int n = jb >> 2;
    const float4 bs = *(const float4*)(p.bsum + jb);
#pragma unroll
    for (int j = 0; j < 4; ++j) {
      const int m = m0 + wc * 64 + j * 16 + lr;
      const int idx = m * H_ + n;
      const float gi = acc[i][j][0] + bs.x;
      const float gf = acc[i][j][1] + bs.y;
      const float gg = acc[i][j][2] + bs.z;
      const float go = acc[i][j][3] + bs.w;
      const float cn = sigm(gf) * p.c[idx] + sigm(gi) * tanhfast(gg);
      const float hn = sigm(go) * tanhfast(cn);
      p.c[idx] = cn;
      p.h_out[idx] = hn;
    }
  }
}

// ---------------------------------------------------------------------------
// Normal-orientation output GEMM (bf16 MFMA): C[m][v] = act[m]·W[v] + bias[v].
// Optional fused LN on act (mean != null): act = LN(concat(A0,A1)) affine.
// Coalesced fp32 C stores.
// ---------------------------------------------------------------------------
struct OP {
  const float* A0; const float* A1;
  const float* mean; const float* rstd; const float* lng; const float* lnb;
  const u16* W;        // N x K bf16
  const float* bias;   // N fp32
  float* Cf; int ldc;
  int K;
};

__launch_bounds__(256)
__global__ void out_mfma_k(OP p0, OP p1) {
  OP p = blockIdx.z ? p1 : p0;
  __shared__ u16 Ws[128 * 40];
  __shared__ u16 As[128 * 40];
  const int tid = threadIdx.x;
  const int lane = tid & 63, wave = tid >> 6;
  const int wr = wave & 1, wc = wave >> 1;      // wr: batch sub, wc: v sub
  const int v0 = blockIdx.x * 128, m0 = blockIdx.y * 128;
  const int lr = lane & 15, lk = (lane >> 4) * 8;

  f32x4 acc[4][4] = {};

  for (int k0 = 0; k0 < p.K; k0 += 32) {
    uint4 wv[2]; float4 alo[2], ahi[2];
#pragma unroll
    for (int cc = 0; cc < 2; ++cc) {
      const int ch = tid + cc * 256;
      const int row = ch >> 2, kc = (ch & 3) * 8;
      const int k = k0 + kc;
      wv[cc] = *(const uint4*)(p.W + (v0 + row) * p.K + k);
      if (p.mean) {
        const int m = m0 + row;
        const float* sx = (k < H_) ? (p.A0 + m * H_ + k) : (p.A1 + m * H_ + (k - H_));
        const float4 xl = *(const float4*)sx, xh = *(const float4*)(sx + 4);
        const float4 gl = *(const float4*)(p.lng + k), gh = *(const float4*)(p.lng + k + 4);
        const float4 bl = *(const float4*)(p.lnb + k), bh = *(const float4*)(p.lnb + k + 4);
        const float rm = p.mean[m], rs = p.rstd[m];
        alo[cc].x = (xl.x - rm) * rs * gl.x + bl.x;
        alo[cc].y = (xl.y - rm) * rs * gl.y + bl.y;
        alo[cc].z = (xl.z - rm) * rs * gl.z + bl.z;
        alo[cc].w = (xl.w - rm) * rs * gl.w + bl.w;
        ahi[cc].x = (xh.x - rm) * rs * gh.x + bh.x;
        ahi[cc].y = (xh.y - rm) * rs * gh.y + bh.y;
        ahi[cc].z = (xh.z - rm) * rs * gh.z + bh.z;
        ahi[cc].w = (xh.w - rm) * rs * gh.w + bh.w;
      } else {
        const float* sx = p.A0 + (m0 + row) * H_ + k;
        alo[cc] = *(const float4*)sx; ahi[cc] = *(const float4*)(sx + 4);
      }
    }
    __syncthreads();
#pragma unroll
    for (int cc = 0; cc < 2; ++cc) {
      const int ch = tid + cc * 256;
      const int row = ch >> 2, kc = (ch & 3) * 8;
      *(uint4*)(Ws + row * 40 + kc) = wv[cc];
      st8bf(As + row * 40 + kc, alo[cc], ahi[cc]);
    }
    __syncthreads();
    bf16x8 aa[4], bb[4];
#pragma unroll
    for (int t = 0; t < 4; ++t) {
      aa[t] = *(const bf16x8*)(As + (wr * 64 + t * 16 + lr) * 40 + lk);
      bb[t] = *(const bf16x8*)(Ws + (wc * 64 + t * 16 + lr) * 40 + lk);
    }
#pragma unroll
    for (int i = 0; i < 4; ++i)
#pragma unroll
      for (int j = 0; j < 4; ++j)
        acc[i][j] = __builtin_amdgcn_mfma_f32_16x16x32_bf16(aa[i], bb[j], acc[i][j], 0, 0, 0);
  }

#pragma unroll
  for (int j = 0; j < 4; ++j) {
    const int v = v0 + wc * 64 + j * 16 + lr;
    const float bv = p.bias[v];
#pragma unroll
    for (int i = 0; i < 4; ++i) {
      const int mb = m0 + wr * 64 + i * 16 + (lane >> 4) * 4;
#pragma unroll
      for (int r = 0; r < 4; ++r)
        p.Cf[(mb + r) * p.ldc + v] = acc[i][j][r] + bv;
    }
  }
}

// ---- prep: gate-interleaved bf16 weight + combined bias ---------------------
__global__ void prep_gates_k(const float* Wih, const float* Whh,
                             const float* b1, const float* b2,
                             u16* Wout, float* bsum, int KI, int K) {
  const int j = blockIdx.y;
  const int k = blockIdx.x * 256 + threadIdx.x;
  const int worig = (j & 3) * H_ + (j >> 2);
  const float v = (k < KI) ? Wih[worig * KI + k] : Whh[worig * H_ + (k - KI)];
  Wout[(long)j * K + k] = f2b(v);
  if (k == 0) bsum[j] = b1[worig] + b2[worig];
}

__global__ void cast_k(const float* s, u16* d) {
  const int i = blockIdx.x * 256 + threadIdx.x;
  d[i] = f2b(s[i]);
}

__global__ void init_k(float* a, float* b, float* c, float* d) {
  const int i = blockIdx.x * 256 + threadIdx.x;
  a[i] = 0.f; b[i] = 0.f; c[i] = 0.f; d[i] = 0.f;
}

__global__ void cast_feat_k(const int* f, float* o) {
  const int i = blockIdx.x * 256 + threadIdx.x;
  o[i] = b2f(f2b((float)f[i]));
}

__global__ void ln_stats_k(const float* hf, const float* hb, float* mean, float* rstd) {
  const int b = blockIdx.x, t = threadIdx.x;
  float s = 0.f, sq = 0.f;
#pragma unroll
  for (int j = 0; j < 4; ++j) {
    const int k = t + 256 * j;
    const float v = (k < H_) ? hf[b * H_ + k] : hb[b * H_ + (k - H_)];
    s += v; sq += v * v;
  }
#pragma unroll
  for (int off = 32; off; off >>= 1) {
    s += __shfl_down(s, off);
    sq += __shfl_down(sq, off);
  }
  __shared__ float ss[4], ssq[4];
  if ((t & 63) == 0) { ss[t >> 6] = s; ssq[t >> 6] = sq; }
  __syncthreads();
  if (t == 0) {
    const float S = ss[0] + ss[1] + ss[2] + ss[3];
    const float SQ = ssq[0] + ssq[1] + ssq[2] + ssq[3];
    const float m = S * (1.f / 1024.f);
    const float var = SQ * (1.f / 1024.f) - m * m;
    mean[b] = m;
    rstd[b] = rsqrtf(var + 1e-5f);
  }
}

__global__ void z_k(const float* mu, const float* lv, const float* eps,
                    float* dh, float* dc) {
  const int i = blockIdx.x * 256 + threadIdx.x;
  const float z = mu[i] + __expf(0.5f * lv[i]) * eps[i];
  dh[i] = z; dc[i] = z;
}

extern "C" void kernel_launch(void* const* d_in, const int* in_sizes, int n_in,
                              void* d_out, int out_size, void* d_ws, size_t ws_size,
                              hipStream_t stream) {
  const int*   features = (const int*)d_in[0];
  const float* eps      = (const float*)d_in[1];
  const float* emb      = (const float*)d_in[2];
  const float* eWih_f   = (const float*)d_in[3];
  const float* eWhh_f   = (const float*)d_in[4];
  const float* ebih_f   = (const float*)d_in[5];
  const float* ebhh_f   = (const float*)d_in[6];
  const float* eWih_b   = (const float*)d_in[7];
  const float* eWhh_b   = (const float*)d_in[8];
  const float* ebih_b   = (const float*)d_in[9];
  const float* ebhh_b   = (const float*)d_in[10];
  const float* dWhh     = (const float*)d_in[12];
  const float* dbih     = (const float*)d_in[13];
  const float* dbhh     = (const float*)d_in[14];
  const float* mu_ln_g  = (const float*)d_in[15];
  const float* mu_ln_b  = (const float*)d_in[16];
  const float* mu_W     = (const float*)d_in[17];
  const float* mu_b     = (const float*)d_in[18];
  const float* lv_ln_g  = (const float*)d_in[19];
  const float* lv_ln_b  = (const float*)d_in[20];
  const float* lv_W     = (const float*)d_in[21];
  const float* lv_b     = (const float*)d_in[22];
  const float* ff_W     = (const float*)d_in[23];
  const float* ff_b     = (const float*)d_in[24];

  // d_out FP32: [features 65536 | features_hat 14680064 | mu 1048576 | lv 1048576]
  float* of = (float*)d_out;
  float* o_feat = of;
  float* o_fh   = of + (B_ * L_);
  float* o_mu   = o_fh + (long)B_ * DEC_T_ * V_;
  float* o_lv   = o_mu + (long)B_ * H_;

  // ws: 6 fp32 state arrays (24MB) + bf16 weights (~11.5MB) + small fp32
  const int NA = B_ * H_;
  float* hf0 = (float*)d_ws;
  float* hf1 = hf0 + NA;
  float* hb0 = hf1 + NA;
  float* hb1 = hb0 + NA;
  float* cf  = hb1 + NA;
  float* cb  = cf  + NA;
  u16* Wenc_f = (u16*)(cb + NA);            // 2048*768
  u16* Wenc_b = Wenc_f + 2048 * 768;        // 2048*768
  u16* Wdec   = Wenc_b + 2048 * 768;        // 2048*512
  u16* Wff    = Wdec + 2048 * 512;          // 1024*512
  u16* Wmu    = Wff + 1024 * 512;           // 512*1024
  u16* Wlv    = Wmu + 512 * 1024;           // 512*1024
  float* bsum_f = (float*)(Wlv + 512 * 1024);  // 2048
  float* bsum_b = bsum_f + 2048;
  float* bsum_d = bsum_b + 2048;
  float* mean   = bsum_d + 2048;
  float* rstd   = mean + B_;

  cast_feat_k<<<dim3(B_ * L_ / 256), dim3(256), 0, stream>>>(features, o_feat);
  init_k<<<dim3(NA / 256), dim3(256), 0, stream>>>(hf0, hb0, cf, cb);

  // ---- weight prep (bf16, gate-interleaved) --------------------------------
  prep_gates_k<<<dim3(3, 2048), dim3(256), 0, stream>>>(eWih_f, eWhh_f, ebih_f, ebhh_f, Wenc_f, bsum_f, E_, E_ + H_);
  prep_gates_k<<<dim3(3, 2048), dim3(256), 0, stream>>>(eWih_b, eWhh_b, ebih_b, ebhh_b, Wenc_b, bsum_b, E_, E_ + H_);
  prep_gates_k<<<dim3(2, 2048), dim3(256), 0, stream>>>(nullptr, dWhh, dbih, dbhh, Wdec, bsum_d, 0, H_);
  cast_k<<<dim3(1024 * 512 / 256), dim3(256), 0, stream>>>(ff_W, Wff);
  cast_k<<<dim3(512 * 1024 / 256), dim3(256), 0, stream>>>(mu_W, Wmu);
  cast_k<<<dim3(512 * 1024 / 256), dim3(256), 0, stream>>>(lv_W, Wlv);

  // ---- encoder: 32 dual-direction fused MFMA steps -------------------------
  for (int s = 0; s < L_; ++s) {
    LP pf{}, pb{};
    pf.feat = features + s;              pb.feat = features + (L_ - 1 - s);
    pf.emb = emb;                        pb.emb = emb;
    pf.h_in  = (s & 1) ? hf1 : hf0;      pb.h_in  = (s & 1) ? hb1 : hb0;
    pf.h_out = (s & 1) ? hf0 : hf1;      pb.h_out = (s & 1) ? hb0 : hb1;
    pf.W = Wenc_f;  pf.bsum = bsum_f;    pb.W = Wenc_b;  pb.bsum = bsum_b;
    pf.c = cf;                           pb.c = cb;
    pf.K = E_ + H_;                      pb.K = E_ + H_;
    lstm_mfma_k<<<dim3(16, 16, 2), dim3(256), 0, stream>>>(pf, pb);
  }
  // 32 (even) steps: final fwd h in hf0, bwd h in hb0.

  // ---- LN stats + mu/lv heads ----------------------------------------------
  ln_stats_k<<<dim3(B_), dim3(256), 0, stream>>>(hf0, hb0, mean, rstd);
  {
    OP pm{}, pl{};
    pm.A0 = hf0; pm.A1 = hb0;
    pm.mean = mean; pm.rstd = rstd; pm.lng = mu_ln_g; pm.lnb = mu_ln_b;
    pm.W = Wmu; pm.bias = mu_b;
    pm.Cf = o_mu; pm.ldc = H_;
    pm.K = 2 * H_;
    pl = pm;
    pl.lng = lv_ln_g; pl.lnb = lv_ln_b;
    pl.W = Wlv; pl.bias = lv_b;
    pl.Cf = o_lv;
    out_mfma_k<<<dim3(4, 16, 2), dim3(256), 0, stream>>>(pm, pl);
  }
  z_k<<<dim3(NA / 256), dim3(256), 0, stream>>>(o_mu, o_lv, eps, hf1, hb1);

  // ---- decoder: 7 fused MFMA steps + ff projection -------------------------
  for (int t = 0; t < DEC_T_; ++t) {
    LP pg{};
    pg.feat = nullptr; pg.emb = nullptr;
    pg.h_in  = (t & 1) ? hf0 : hf1;
    pg.h_out = (t & 1) ? hf1 : hf0;
    pg.W = Wdec; pg.bsum = bsum_d;
    pg.c = hb1;
    pg.K = H_;
    lstm_mfma_k<<<dim3(16, 16, 1), dim3(256), 0, stream>>>(pg, pg);

    OP po{};
    po.A0 = pg.h_out; po.A1 = nullptr;
    po.mean = nullptr; po.rstd = nullptr; po.lng = nullptr; po.lnb = nullptr;
    po.W = Wff; po.bias = ff_b;
    po.Cf = o_fh + (long)t * V_; po.ldc = DEC_T_ * V_;
    po.K = H_;
    out_mfma_k<<<dim3(8, 16, 1), dim3(256), 0, stream>>>(po, po);
  }
}